// Round 1
// 2659.511 us; speedup vs baseline: 1.0025x; 1.0025x over previous
//
#include <hip/hip_runtime.h>

// ManifoldRNN: B=64, S=2048, I=H=O=256, L=2.
// Plan:
//   1) prep:     swizzle w_h0, w_q (fp32) -> fp16 MFMA-B-fragment layout in ws
//   2) gemm256<A=fp32,C=fp16>: A0[b,t,:] = x@w_h0 + b_h0   (fp16, ws or d_out-low)
//   3) rnn:      64 persistent blocks (1/batch), 12 waves, weights fp16 in VGPRs,
//                v_dot2_f32_f16 matvecs, 1 __syncthreads per step, software-pipelined
//                (L0 | w_h1-partial | u_h1+finalize). Writes H1_all fp16 + h_final fp32.
//   4) gemm256<A=fp16,C=fp32>: y = H1_all@w_q + b_q -> d_out
//
// R1 change: __launch_bounds__(768, 3) on rnn_kernel. With bare
// __launch_bounds__(768) the backend targeted ~6 waves/EU (2 blocks/CU) and
// capped the allocator at ~85 VGPRs (measured VGPR_Count=84), spilling the
// w[128] register-resident weight column to scratch — ~128 scratch reloads
// per wave per step. Grid is only 64 blocks (1/batch), so >1 block/CU can
// never be resident anyway; minWavesPerEU=3 (= exactly one 12-wave block per
// CU) raises the register budget to 512/3≈170 so w[] genuinely lives in VGPRs.
#define S_LEN 2048
#define NB    64
#define HD    256

typedef _Float16 half2_t  __attribute__((ext_vector_type(2)));
typedef _Float16 half8_t  __attribute__((ext_vector_type(8)));
typedef float    floatx4  __attribute__((ext_vector_type(4)));
typedef float    floatx8  __attribute__((ext_vector_type(8)));
typedef float    floatx16 __attribute__((ext_vector_type(16)));

__device__ __forceinline__ float fdot2(half2_t a, half2_t b, float c){
#if __has_builtin(__builtin_amdgcn_fdot2)
  return __builtin_amdgcn_fdot2(a, b, c, false);
#else
  return c + (float)a[0]*(float)b[0] + (float)a[1]*(float)b[1];
#endif
}

__device__ __forceinline__ float tanh_fast(float x){
  // tanh(x) = 1 - 2/(e^{2x}+1); |preact| <~ 10 so no overflow issues, saturates correctly.
  float e = __expf(2.0f * x);
  return 1.0f - 2.0f / (e + 1.0f);
}

// Full-K (256) fp16 dot-product of LDS-broadcast h against per-lane register column.
// HS: const half8_t* into LDS (same address for all lanes -> broadcast reads).
// WREG: half2_t[128] register-resident column. 4 accumulators hide VALU latency.
#define MATVEC(HS, WREG, ACC)                                                     \
  {                                                                               \
    float a0_=0.f, a1_=0.f, a2_=0.f, a3_=0.f;                                     \
    _Pragma("unroll")                                                             \
    for (int i_ = 0; i_ < 32; ++i_){                                              \
      half8_t c_ = (HS)[i_];                                                      \
      a0_ = fdot2(__builtin_shufflevector(c_, c_, 0, 1), (WREG)[4*i_+0], a0_);    \
      a1_ = fdot2(__builtin_shufflevector(c_, c_, 2, 3), (WREG)[4*i_+1], a1_);    \
      a2_ = fdot2(__builtin_shufflevector(c_, c_, 4, 5), (WREG)[4*i_+2], a2_);    \
      a3_ = fdot2(__builtin_shufflevector(c_, c_, 6, 7), (WREG)[4*i_+3], a3_);    \
    }                                                                             \
    ACC = (a0_ + a1_) + (a2_ + a3_);                                              \
  }

// ---------------------------------------------------------------------------
// Persistent recurrence kernel: one block per batch element.
// 12 waves: group0 (waves 0-3):  h0n(tau)      = tanh(A0(tau) + h0(tau-1)@u_h0)
//           group2 (waves 8-11): wpart(tau-1)  = h0n(tau-1)@w_h1
//           group1 (waves 4-7):  h1(tau-2)@u_h1 + wpart + b_h1 -> tanh -> h1, H1_all
// ---------------------------------------------------------------------------
__launch_bounds__(768, 3)
__global__ void rnn_kernel(const _Float16* __restrict__ A0,
                           const float* __restrict__ u_h0,
                           const float* __restrict__ w_h1,
                           const float* __restrict__ u_h1,
                           const float* __restrict__ b_h1,
                           _Float16* __restrict__ H1,
                           float* __restrict__ hfinal)
{
  const int b    = blockIdx.x;
  const int tid  = threadIdx.x;
  const int wave = tid >> 6;
  const int lane = tid & 63;
  const int group = wave >> 2;                 // 0,1,2 as above
  const int col   = ((wave & 3) << 6) | lane;  // 0..255

  __shared__ __align__(16) _Float16 h0buf[2][HD];
  __shared__ __align__(16) _Float16 h1buf[2][HD];
  __shared__ __align__(16) float    wpart[2][HD];

  if (tid < HD){
    h0buf[0][tid] = (_Float16)0.f; h0buf[1][tid] = (_Float16)0.f;
    h1buf[0][tid] = (_Float16)0.f; h1buf[1][tid] = (_Float16)0.f;
    wpart[0][tid] = 0.f;           wpart[1][tid] = 0.f;
  }

  // Register-resident fp16 weight column (k-major pairs). Coalesced per-k loads.
  const float* Wm = (group == 0) ? u_h0 : (group == 1) ? u_h1 : w_h1;
  half2_t w[128];
  #pragma unroll
  for (int i = 0; i < 128; ++i){
    float w0 = Wm[(2*i)     * HD + col];
    float w1 = Wm[(2*i + 1) * HD + col];
    half2_t p; p[0] = (_Float16)w0; p[1] = (_Float16)w1;
    w[i] = p;
  }

  const size_t base = (size_t)b * S_LEN * HD;
  const float bias = (group == 1) ? b_h1[col] : 0.f;   // b_h0 is folded into A0

  _Float16 a0p0 = (_Float16)0.f, a0p1 = (_Float16)0.f; // depth-2 A0 prefetch
  if (group == 0){
    a0p0 = A0[base + 0 * HD + col];
    a0p1 = A0[base + 1 * HD + col];
  }

  __syncthreads();

  for (int tau = 0; tau < S_LEN + 2; ++tau){
    if (group == 0){
      if (tau < S_LEN){
        const half8_t* hs = (const half8_t*)(&h0buf[(tau + 1) & 1][0]);
        float acc; MATVEC(hs, w, acc);
        float h = tanh_fast(acc + (float)a0p0);
        h0buf[tau & 1][col] = (_Float16)h;
        if (tau == S_LEN - 1) hfinal[(b << 9) + col] = h;
        a0p0 = a0p1;
        if (tau + 2 < S_LEN) a0p1 = A0[base + (size_t)(tau + 2) * HD + col];
      }
    } else if (group == 2){
      const int t1 = tau - 1;
      if (t1 >= 0 && t1 < S_LEN){
        const half8_t* hs = (const half8_t*)(&h0buf[t1 & 1][0]);
        float acc; MATVEC(hs, w, acc);
        wpart[t1 & 1][col] = acc;
      }
    } else {
      const int t = tau - 2;
      if (t >= 0){
        const half8_t* hs = (const half8_t*)(&h1buf[(t + 1) & 1][0]);
        float acc; MATVEC(hs, w, acc);
        float h = tanh_fast(acc + wpart[t & 1][col] + bias);
        h1buf[t & 1][col] = (_Float16)h;
        H1[base + (size_t)t * HD + col] = (_Float16)h;
        if (t == S_LEN - 1) hfinal[(b << 9) + HD + col] = h;
      }
    }
    __syncthreads();
  }
}

// ---------------------------------------------------------------------------
// Swizzle B (fp32 [256,256] row-major) into fp16 MFMA-B-fragment-contiguous
// layout: sw = (k>>3)*2048 + n*8 + (k&7). Frag load = one 16B coalesced read.
// ---------------------------------------------------------------------------
__global__ void prep_kernel(const float* __restrict__ w0, const float* __restrict__ wq,
                            _Float16* __restrict__ B0, _Float16* __restrict__ Bq)
{
  int i = blockIdx.x * 256 + threadIdx.x;
  for (int idx = i; idx < 65536; idx += 64 * 256){
    int k = idx >> 8, n = idx & 255;
    int sw = (k >> 3) * 2048 + n * 8 + (k & 7);
    B0[sw] = (_Float16)w0[idx];
    Bq[sw] = (_Float16)wq[idx];
  }
}

// ---------------------------------------------------------------------------
// C[131072,256] = A[131072,256] @ B[256,256] + bias, fp16 MFMA 32x32x16.
// 512 blocks x 512 thr; each wave owns a 32-row x 256-col strip (8 col-tiles,
// 128 acc VGPRs). A-frags direct from global; B-frags from pre-swizzled global
// fp16 (L2-resident), perfectly coalesced. No LDS.
// ---------------------------------------------------------------------------
template<bool A_FP32, bool C_FP16>
__launch_bounds__(512)
__global__ void gemm256(const void* __restrict__ Ap,
                        const _Float16* __restrict__ Bsw,
                        const float* __restrict__ bias,
                        void* __restrict__ Cp)
{
  const int wave = threadIdx.x >> 6;
  const int lane = threadIdx.x & 63;
  const int r  = lane & 31;     // A row / B col / C col within tile
  const int hf = lane >> 5;     // k-half selector
  const size_t rowt = (size_t)blockIdx.x * 256 + (size_t)wave * 32;

  floatx16 acc[8];
  #pragma unroll
  for (int i = 0; i < 8; ++i)
    #pragma unroll
    for (int j = 0; j < 16; ++j) acc[i][j] = 0.f;

  const size_t arow = rowt + (size_t)r;
  #pragma unroll
  for (int ks = 0; ks < 16; ++ks){
    half8_t af;
    if (A_FP32){
      const float* A = (const float*)Ap;
      const floatx4* p = (const floatx4*)(A + arow * 256 + ks * 16 + hf * 8);
      floatx4 v0 = p[0], v1 = p[1];
      floatx8 v = __builtin_shufflevector(v0, v1, 0, 1, 2, 3, 4, 5, 6, 7);
      af = __builtin_convertvector(v, half8_t);
    } else {
      const _Float16* A = (const _Float16*)Ap;
      af = *(const half8_t*)(A + arow * 256 + ks * 16 + hf * 8);
    }
    #pragma unroll
    for (int ct = 0; ct < 8; ++ct){
      half8_t bf = *(const half8_t*)(Bsw + (size_t)(ks * 2 + hf) * 2048 + (ct * 32 + r) * 8);
      acc[ct] = __builtin_amdgcn_mfma_f32_32x32x16_f16(af, bf, acc[ct], 0, 0, 0);
    }
  }

  #pragma unroll
  for (int ct = 0; ct < 8; ++ct){
    const int col = ct * 32 + r;
    const float bc = bias[col];
    #pragma unroll
    for (int reg = 0; reg < 16; ++reg){
      const int rl = (reg & 3) + 8 * (reg >> 2) + 4 * hf;   // verified 32x32 C/D map
      const size_t idx = (rowt + rl) * 256 + col;
      float v = acc[ct][reg] + bc;
      if (C_FP16) ((_Float16*)Cp)[idx] = (_Float16)v;
      else        ((float*)Cp)[idx]    = v;
    }
  }
}

extern "C" void kernel_launch(void* const* d_in, const int* in_sizes, int n_in,
                              void* d_out, int out_size, void* d_ws, size_t ws_size,
                              hipStream_t stream)
{
  (void)in_sizes; (void)n_in; (void)out_size;

  const float* x    = (const float*)d_in[0];
  const float* w_h0 = (const float*)d_in[1];
  const float* u_h0 = (const float*)d_in[2];
  const float* b_h0 = (const float*)d_in[3];
  const float* w_h1 = (const float*)d_in[4];
  const float* u_h1 = (const float*)d_in[5];
  const float* b_h1 = (const float*)d_in[6];
  const float* w_q  = (const float*)d_in[7];
  const float* b_q  = (const float*)d_in[8];

  const size_t MSH = (size_t)NB * S_LEN * HD;          // 33,554,432 elements
  float* y    = (float*)d_out;                         // [B,S,O] fp32
  float* hfin = y + MSH;                               // [B,2,H] fp32

  // Scratch layout. H1 always in ws. A0 in ws if it fits, else in d_out's low
  // half (A0 fully consumed by rnn before the Y-GEMM overwrites d_out).
  _Float16* H1 = (_Float16*)d_ws;
  _Float16 *A0, *B0sw, *Bqsw;
  if (ws_size >= (MSH * 2 + 2 * 65536) * sizeof(_Float16)){
    A0   = H1 + MSH;
    B0sw = A0 + MSH;
    Bqsw = B0sw + 65536;
  } else {
    A0   = (_Float16*)d_out;    // 67MB fp16 in the 134MB output buffer
    B0sw = H1 + MSH;
    Bqsw = B0sw + 65536;
  }

  prep_kernel<<<dim3(64), dim3(256), 0, stream>>>(w_h0, w_q, B0sw, Bqsw);
  gemm256<true, true><<<dim3(512), dim3(512), 0, stream>>>((const void*)x, B0sw, b_h0, (void*)A0);
  rnn_kernel<<<dim3(NB), dim3(768), 0, stream>>>(A0, u_h0, w_h1, u_h1, b_h1, H1, hfin);
  gemm256<false, false><<<dim3(512), dim3(512), 0, stream>>>((const void*)H1, Bqsw, b_q, (void*)y);
}

// Round 2
// 2640.418 us; speedup vs baseline: 1.0098x; 1.0072x over previous
//
#include <hip/hip_runtime.h>

// ManifoldRNN: B=64, S=2048, I=H=O=256, L=2.
// Plan:
//   1) prep:     swizzle w_h0, w_q (fp32) -> fp16 MFMA-B-fragment layout in ws
//   2) gemm256<A=fp32,C=fp16>: A0[b,t,:] = x@w_h0 + b_h0   (fp16, ws or d_out-low)
//   3) rnn:      64 persistent blocks (1/batch), 12 waves, weights fp16 in VGPRs,
//                v_dot2_f32_f16 matvecs, 1 __syncthreads per step, software-pipelined
//                (L0 | w_h1-partial | u_h1+finalize). Writes H1_all fp16 + h_final fp32.
//   4) gemm256<A=fp16,C=fp32>: y = H1_all@w_q + b_q -> d_out
//
// R2 change: force w[128] to actually live in VGPRs.
//   - R1's __launch_bounds__(768,3) raised the *allowed* VGPR budget but the
//     allocator still chose 84 (≈512/6 → 6 waves/EU target): min-waves only
//     bounds below; the scheduler still chases occupancy and sinks the
//     (restrict-const, hence rematerializable) weight loads into the tau loop.
//   - amdgpu_waves_per_eu(3,3) pins max waves/EU = 3 (grid is 64 blocks — one
//     12-wave block per CU is all that can ever be resident, so this costs
//     nothing) => scheduler targets the full 512/3≈170 VGPR budget.
//   - asm volatile "+v" pin on each w[i] forces materialization before the
//     loop, blocking sink/remat regardless of cost model.
#define S_LEN 2048
#define NB    64
#define HD    256

typedef _Float16 half2_t  __attribute__((ext_vector_type(2)));
typedef _Float16 half8_t  __attribute__((ext_vector_type(8)));
typedef float    floatx4  __attribute__((ext_vector_type(4)));
typedef float    floatx8  __attribute__((ext_vector_type(8)));
typedef float    floatx16 __attribute__((ext_vector_type(16)));

__device__ __forceinline__ float fdot2(half2_t a, half2_t b, float c){
#if __has_builtin(__builtin_amdgcn_fdot2)
  return __builtin_amdgcn_fdot2(a, b, c, false);
#else
  return c + (float)a[0]*(float)b[0] + (float)a[1]*(float)b[1];
#endif
}

__device__ __forceinline__ float tanh_fast(float x){
  // tanh(x) = 1 - 2/(e^{2x}+1); |preact| <~ 10 so no overflow issues, saturates correctly.
  float e = __expf(2.0f * x);
  return 1.0f - 2.0f / (e + 1.0f);
}

// Full-K (256) fp16 dot-product of LDS-broadcast h against per-lane register column.
// HS: const half8_t* into LDS (same address for all lanes -> broadcast reads).
// WREG: half2_t[128] register-resident column. 4 accumulators hide VALU latency.
#define MATVEC(HS, WREG, ACC)                                                     \
  {                                                                               \
    float a0_=0.f, a1_=0.f, a2_=0.f, a3_=0.f;                                     \
    _Pragma("unroll")                                                             \
    for (int i_ = 0; i_ < 32; ++i_){                                              \
      half8_t c_ = (HS)[i_];                                                      \
      a0_ = fdot2(__builtin_shufflevector(c_, c_, 0, 1), (WREG)[4*i_+0], a0_);    \
      a1_ = fdot2(__builtin_shufflevector(c_, c_, 2, 3), (WREG)[4*i_+1], a1_);    \
      a2_ = fdot2(__builtin_shufflevector(c_, c_, 4, 5), (WREG)[4*i_+2], a2_);    \
      a3_ = fdot2(__builtin_shufflevector(c_, c_, 6, 7), (WREG)[4*i_+3], a3_);    \
    }                                                                             \
    ACC = (a0_ + a1_) + (a2_ + a3_);                                              \
  }

// ---------------------------------------------------------------------------
// Persistent recurrence kernel: one block per batch element.
// 12 waves: group0 (waves 0-3):  h0n(tau)      = tanh(A0(tau) + h0(tau-1)@u_h0)
//           group2 (waves 8-11): wpart(tau-1)  = h0n(tau-1)@w_h1
//           group1 (waves 4-7):  h1(tau-2)@u_h1 + wpart + b_h1 -> tanh -> h1, H1_all
// ---------------------------------------------------------------------------
__attribute__((amdgpu_flat_work_group_size(768, 768)))
__attribute__((amdgpu_waves_per_eu(3, 3)))
__global__ void rnn_kernel(const _Float16* __restrict__ A0,
                           const float* __restrict__ u_h0,
                           const float* __restrict__ w_h1,
                           const float* __restrict__ u_h1,
                           const float* __restrict__ b_h1,
                           _Float16* __restrict__ H1,
                           float* __restrict__ hfinal)
{
  const int b    = blockIdx.x;
  const int tid  = threadIdx.x;
  const int wave = tid >> 6;
  const int lane = tid & 63;
  const int group = wave >> 2;                 // 0,1,2 as above
  const int col   = ((wave & 3) << 6) | lane;  // 0..255

  __shared__ __align__(16) _Float16 h0buf[2][HD];
  __shared__ __align__(16) _Float16 h1buf[2][HD];
  __shared__ __align__(16) float    wpart[2][HD];

  if (tid < HD){
    h0buf[0][tid] = (_Float16)0.f; h0buf[1][tid] = (_Float16)0.f;
    h1buf[0][tid] = (_Float16)0.f; h1buf[1][tid] = (_Float16)0.f;
    wpart[0][tid] = 0.f;           wpart[1][tid] = 0.f;
  }

  // Register-resident fp16 weight column (k-major pairs). Coalesced per-k loads.
  const float* Wm = (group == 0) ? u_h0 : (group == 1) ? u_h1 : w_h1;
  half2_t w[128];
  #pragma unroll
  for (int i = 0; i < 128; ++i){
    float w0 = Wm[(2*i)     * HD + col];
    float w1 = Wm[(2*i + 1) * HD + col];
    half2_t p; p[0] = (_Float16)w0; p[1] = (_Float16)w1;
    w[i] = p;
  }
  // Pin: force each w[i] into a VGPR here; blocks sink-into-loop remat of the
  // (rematerializable) global weight loads.
  #pragma unroll
  for (int i = 0; i < 128; ++i) asm volatile("" : "+v"(w[i]));

  const size_t base = (size_t)b * S_LEN * HD;
  const float bias = (group == 1) ? b_h1[col] : 0.f;   // b_h0 is folded into A0

  _Float16 a0p0 = (_Float16)0.f, a0p1 = (_Float16)0.f; // depth-2 A0 prefetch
  if (group == 0){
    a0p0 = A0[base + 0 * HD + col];
    a0p1 = A0[base + 1 * HD + col];
  }

  __syncthreads();

  for (int tau = 0; tau < S_LEN + 2; ++tau){
    if (group == 0){
      if (tau < S_LEN){
        const half8_t* hs = (const half8_t*)(&h0buf[(tau + 1) & 1][0]);
        float acc; MATVEC(hs, w, acc);
        float h = tanh_fast(acc + (float)a0p0);
        h0buf[tau & 1][col] = (_Float16)h;
        if (tau == S_LEN - 1) hfinal[(b << 9) + col] = h;
        a0p0 = a0p1;
        if (tau + 2 < S_LEN) a0p1 = A0[base + (size_t)(tau + 2) * HD + col];
      }
    } else if (group == 2){
      const int t1 = tau - 1;
      if (t1 >= 0 && t1 < S_LEN){
        const half8_t* hs = (const half8_t*)(&h0buf[t1 & 1][0]);
        float acc; MATVEC(hs, w, acc);
        wpart[t1 & 1][col] = acc;
      }
    } else {
      const int t = tau - 2;
      if (t >= 0){
        const half8_t* hs = (const half8_t*)(&h1buf[(t + 1) & 1][0]);
        float acc; MATVEC(hs, w, acc);
        float h = tanh_fast(acc + wpart[t & 1][col] + bias);
        h1buf[t & 1][col] = (_Float16)h;
        H1[base + (size_t)t * HD + col] = (_Float16)h;
        if (t == S_LEN - 1) hfinal[(b << 9) + HD + col] = h;
      }
    }
    __syncthreads();
  }
}

// ---------------------------------------------------------------------------
// Swizzle B (fp32 [256,256] row-major) into fp16 MFMA-B-fragment-contiguous
// layout: sw = (k>>3)*2048 + n*8 + (k&7). Frag load = one 16B coalesced read.
// ---------------------------------------------------------------------------
__global__ void prep_kernel(const float* __restrict__ w0, const float* __restrict__ wq,
                            _Float16* __restrict__ B0, _Float16* __restrict__ Bq)
{
  int i = blockIdx.x * 256 + threadIdx.x;
  for (int idx = i; idx < 65536; idx += 64 * 256){
    int k = idx >> 8, n = idx & 255;
    int sw = (k >> 3) * 2048 + n * 8 + (k & 7);
    B0[sw] = (_Float16)w0[idx];
    Bq[sw] = (_Float16)wq[idx];
  }
}

// ---------------------------------------------------------------------------
// C[131072,256] = A[131072,256] @ B[256,256] + bias, fp16 MFMA 32x32x16.
// 512 blocks x 512 thr; each wave owns a 32-row x 256-col strip (8 col-tiles,
// 128 acc VGPRs). A-frags direct from global; B-frags from pre-swizzled global
// fp16 (L2-resident), perfectly coalesced. No LDS.
// ---------------------------------------------------------------------------
template<bool A_FP32, bool C_FP16>
__launch_bounds__(512)
__global__ void gemm256(const void* __restrict__ Ap,
                        const _Float16* __restrict__ Bsw,
                        const float* __restrict__ bias,
                        void* __restrict__ Cp)
{
  const int wave = threadIdx.x >> 6;
  const int lane = threadIdx.x & 63;
  const int r  = lane & 31;     // A row / B col / C col within tile
  const int hf = lane >> 5;     // k-half selector
  const size_t rowt = (size_t)blockIdx.x * 256 + (size_t)wave * 32;

  floatx16 acc[8];
  #pragma unroll
  for (int i = 0; i < 8; ++i)
    #pragma unroll
    for (int j = 0; j < 16; ++j) acc[i][j] = 0.f;

  const size_t arow = rowt + (size_t)r;
  #pragma unroll
  for (int ks = 0; ks < 16; ++ks){
    half8_t af;
    if (A_FP32){
      const float* A = (const float*)Ap;
      const floatx4* p = (const floatx4*)(A + arow * 256 + ks * 16 + hf * 8);
      floatx4 v0 = p[0], v1 = p[1];
      floatx8 v = __builtin_shufflevector(v0, v1, 0, 1, 2, 3, 4, 5, 6, 7);
      af = __builtin_convertvector(v, half8_t);
    } else {
      const _Float16* A = (const _Float16*)Ap;
      af = *(const half8_t*)(A + arow * 256 + ks * 16 + hf * 8);
    }
    #pragma unroll
    for (int ct = 0; ct < 8; ++ct){
      half8_t bf = *(const half8_t*)(Bsw + (size_t)(ks * 2 + hf) * 2048 + (ct * 32 + r) * 8);
      acc[ct] = __builtin_amdgcn_mfma_f32_32x32x16_f16(af, bf, acc[ct], 0, 0, 0);
    }
  }

  #pragma unroll
  for (int ct = 0; ct < 8; ++ct){
    const int col = ct * 32 + r;
    const float bc = bias[col];
    #pragma unroll
    for (int reg = 0; reg < 16; ++reg){
      const int rl = (reg & 3) + 8 * (reg >> 2) + 4 * hf;   // verified 32x32 C/D map
      const size_t idx = (rowt + rl) * 256 + col;
      float v = acc[ct][reg] + bc;
      if (C_FP16) ((_Float16*)Cp)[idx] = (_Float16)v;
      else        ((float*)Cp)[idx]    = v;
    }
  }
}

extern "C" void kernel_launch(void* const* d_in, const int* in_sizes, int n_in,
                              void* d_out, int out_size, void* d_ws, size_t ws_size,
                              hipStream_t stream)
{
  (void)in_sizes; (void)n_in; (void)out_size;

  const float* x    = (const float*)d_in[0];
  const float* w_h0 = (const float*)d_in[1];
  const float* u_h0 = (const float*)d_in[2];
  const float* b_h0 = (const float*)d_in[3];
  const float* w_h1 = (const float*)d_in[4];
  const float* u_h1 = (const float*)d_in[5];
  const float* b_h1 = (const float*)d_in[6];
  const float* w_q  = (const float*)d_in[7];
  const float* b_q  = (const float*)d_in[8];

  const size_t MSH = (size_t)NB * S_LEN * HD;          // 33,554,432 elements
  float* y    = (float*)d_out;                         // [B,S,O] fp32
  float* hfin = y + MSH;                               // [B,2,H] fp32

  // Scratch layout. H1 always in ws. A0 in ws if it fits, else in d_out's low
  // half (A0 fully consumed by rnn before the Y-GEMM overwrites d_out).
  _Float16* H1 = (_Float16*)d_ws;
  _Float16 *A0, *B0sw, *Bqsw;
  if (ws_size >= (MSH * 2 + 2 * 65536) * sizeof(_Float16)){
    A0   = H1 + MSH;
    B0sw = A0 + MSH;
    Bqsw = B0sw + 65536;
  } else {
    A0   = (_Float16*)d_out;    // 67MB fp16 in the 134MB output buffer
    B0sw = H1 + MSH;
    Bqsw = B0sw + 65536;
  }

  prep_kernel<<<dim3(64), dim3(256), 0, stream>>>(w_h0, w_q, B0sw, Bqsw);
  gemm256<true, true><<<dim3(512), dim3(512), 0, stream>>>((const void*)x, B0sw, b_h0, (void*)A0);
  rnn_kernel<<<dim3(NB), dim3(768), 0, stream>>>(A0, u_h0, w_h1, u_h1, b_h1, H1, hfin);
  gemm256<false, false><<<dim3(512), dim3(512), 0, stream>>>((const void*)H1, Bqsw, b_q, (void*)y);
}

// Round 3
// 2594.329 us; speedup vs baseline: 1.0277x; 1.0178x over previous
//
#include <hip/hip_runtime.h>

// ManifoldRNN: B=64, S=2048, I=H=O=256, L=2.
// Plan:
//   1) prep:     swizzle w_h0,w_q AND u_h0,w_h1,u_h1 (fp32) -> fp16
//                fragment-contiguous layout sw=(k>>3)*2048+n*8+(k&7) in ws
//   2) gemm256<A=fp32,C=fp16>: A0[b,t,:] = x@w_h0 + b_h0   (fp16, ws or d_out-low)
//   3) rnn:      64 persistent blocks (1/batch), 12 waves, weights fp16 in
//                32 NAMED half8 VGPR variables, v_dot2_f32_f16 matvecs,
//                1 __syncthreads per step, software-pipelined
//                (L0 | w_h1-partial | u_h1+finalize). Writes H1_all fp16 + h_final fp32.
//   4) gemm256<A=fp16,C=fp32>: y = H1_all@w_q + b_q -> d_out
//
// R3 change: kill the scratch alloca.
//   R1/R2 showed VGPR_Count pinned at 84 regardless of waves_per_eu/launch_bounds/
//   asm pins => the demotion is NOT a register-allocator budget decision. The
//   `half2_t w[128]` (512B/lane) alloca survives SROA (variable index before
//   unroll) and AMDGPU PromoteAlloca rejects it (occupancy-scored budget), so
//   the weight "registers" lived in SCRATCH: 128 dwords/lane scratch reload per
//   MATVEC ~= 22 TB/s of L2 traffic = per-XCD L2 saturation = the measured
//   1.14 us/step. Fix: 32 NAMED half8_t SSA variables (macro-generated, no
//   aggregate => nothing to demote) loaded straight from a prep-converted fp16
//   swizzled weight image as 32 coalesced 16B loads. Loads are not
//   rematerializable and cannot sink; real pressure ~158 < 170 budget at
//   waves_per_eu(3,3).
#define S_LEN 2048
#define NB    64
#define HD    256

typedef _Float16 half2_t  __attribute__((ext_vector_type(2)));
typedef _Float16 half8_t  __attribute__((ext_vector_type(8)));
typedef float    floatx4  __attribute__((ext_vector_type(4)));
typedef float    floatx8  __attribute__((ext_vector_type(8)));
typedef float    floatx16 __attribute__((ext_vector_type(16)));

__device__ __forceinline__ float fdot2(half2_t a, half2_t b, float c){
#if __has_builtin(__builtin_amdgcn_fdot2)
  return __builtin_amdgcn_fdot2(a, b, c, false);
#else
  return c + (float)a[0]*(float)b[0] + (float)a[1]*(float)b[1];
#endif
}

__device__ __forceinline__ float tanh_fast(float x){
  // tanh(x) = 1 - 2/(e^{2x}+1); |preact| <~ 10 so no overflow issues, saturates correctly.
  float e = __expf(2.0f * x);
  return 1.0f - 2.0f / (e + 1.0f);
}

#define FOR32(M) M(0)M(1)M(2)M(3)M(4)M(5)M(6)M(7)M(8)M(9)M(10)M(11)M(12)M(13) \
                 M(14)M(15)M(16)M(17)M(18)M(19)M(20)M(21)M(22)M(23)M(24)M(25) \
                 M(26)M(27)M(28)M(29)M(30)M(31)

#define DECLW(i)  half8_t W##i;
#define LOADW(i)  W##i = *(const half8_t*)(wp + (i)*2048);

// One K-chunk (8 elems) of the dot product: LDS-broadcast half8 c_ against the
// named register half8 W##i, as 4 independent v_dot2_f32_f16 chains.
#define DOT_STEP(i)                                                            \
  { half8_t c_ = hs_[i];                                                       \
    a0_ = fdot2(__builtin_shufflevector(c_, c_, 0, 1),                         \
                __builtin_shufflevector(W##i, W##i, 0, 1), a0_);               \
    a1_ = fdot2(__builtin_shufflevector(c_, c_, 2, 3),                         \
                __builtin_shufflevector(W##i, W##i, 2, 3), a1_);               \
    a2_ = fdot2(__builtin_shufflevector(c_, c_, 4, 5),                         \
                __builtin_shufflevector(W##i, W##i, 4, 5), a2_);               \
    a3_ = fdot2(__builtin_shufflevector(c_, c_, 6, 7),                         \
                __builtin_shufflevector(W##i, W##i, 6, 7), a3_); }

#define MATVEC_W(HS, ACC)                                                      \
  { float a0_=0.f, a1_=0.f, a2_=0.f, a3_=0.f;                                  \
    const half8_t* hs_ = (HS);                                                 \
    FOR32(DOT_STEP)                                                            \
    ACC = (a0_ + a1_) + (a2_ + a3_); }

// ---------------------------------------------------------------------------
// Persistent recurrence kernel: one block per batch element.
// 12 waves: group0 (waves 0-3):  h0n(tau)      = tanh(A0(tau) + h0(tau-1)@u_h0)
//           group2 (waves 8-11): wpart(tau-1)  = h0n(tau-1)@w_h1
//           group1 (waves 4-7):  h1(tau-2)@u_h1 + wpart + b_h1 -> tanh -> h1, H1_all
// Weight image per matrix: fp16, sw=(k>>3)*2048 + col*8 + (k&7): lane `col`
// reads its 256-long column as 32 consecutive 16B chunks at stride 4KB,
// coalesced across lanes.
// ---------------------------------------------------------------------------
__attribute__((amdgpu_flat_work_group_size(768, 768)))
__attribute__((amdgpu_waves_per_eu(3, 3)))
__global__ void rnn_kernel(const _Float16* __restrict__ A0,
                           const _Float16* __restrict__ u0sw,
                           const _Float16* __restrict__ w1sw,
                           const _Float16* __restrict__ u1sw,
                           const float* __restrict__ b_h1,
                           _Float16* __restrict__ H1,
                           float* __restrict__ hfinal)
{
  const int b    = blockIdx.x;
  const int tid  = threadIdx.x;
  const int wave = tid >> 6;
  const int lane = tid & 63;
  const int group = wave >> 2;                 // 0,1,2 as above
  const int col   = ((wave & 3) << 6) | lane;  // 0..255

  __shared__ __align__(16) _Float16 h0buf[2][HD];
  __shared__ __align__(16) _Float16 h1buf[2][HD];
  __shared__ __align__(16) float    wpart[2][HD];

  if (tid < HD){
    h0buf[0][tid] = (_Float16)0.f; h0buf[1][tid] = (_Float16)0.f;
    h1buf[0][tid] = (_Float16)0.f; h1buf[1][tid] = (_Float16)0.f;
    wpart[0][tid] = 0.f;           wpart[1][tid] = 0.f;
  }

  // 32 named half8 weight registers (128 VGPRs), loaded once. No array, no
  // alloca, nothing PromoteAlloca can demote to scratch.
  const _Float16* Wsw = (group == 0) ? u0sw : (group == 1) ? u1sw : w1sw;
  const _Float16* wp  = Wsw + col * 8;
  FOR32(DECLW)
  FOR32(LOADW)

  const size_t base = (size_t)b * S_LEN * HD;
  const float bias = (group == 1) ? b_h1[col] : 0.f;   // b_h0 is folded into A0

  _Float16 a0p0 = (_Float16)0.f, a0p1 = (_Float16)0.f; // depth-2 A0 prefetch
  if (group == 0){
    a0p0 = A0[base + 0 * HD + col];
    a0p1 = A0[base + 1 * HD + col];
  }

  __syncthreads();

  for (int tau = 0; tau < S_LEN + 2; ++tau){
    if (group == 0){
      if (tau < S_LEN){
        float acc; MATVEC_W((const half8_t*)(&h0buf[(tau + 1) & 1][0]), acc);
        float h = tanh_fast(acc + (float)a0p0);
        h0buf[tau & 1][col] = (_Float16)h;
        if (tau == S_LEN - 1) hfinal[(b << 9) + col] = h;
        a0p0 = a0p1;
        if (tau + 2 < S_LEN) a0p1 = A0[base + (size_t)(tau + 2) * HD + col];
      }
    } else if (group == 2){
      const int t1 = tau - 1;
      if (t1 >= 0 && t1 < S_LEN){
        float acc; MATVEC_W((const half8_t*)(&h0buf[t1 & 1][0]), acc);
        wpart[t1 & 1][col] = acc;
      }
    } else {
      const int t = tau - 2;
      if (t >= 0){
        float acc; MATVEC_W((const half8_t*)(&h1buf[(t + 1) & 1][0]), acc);
        float h = tanh_fast(acc + wpart[t & 1][col] + bias);
        h1buf[t & 1][col] = (_Float16)h;
        H1[base + (size_t)t * HD + col] = (_Float16)h;
        if (t == S_LEN - 1) hfinal[(b << 9) + HD + col] = h;
      }
    }
    __syncthreads();
  }
}

// ---------------------------------------------------------------------------
// Swizzle 5 matrices (fp32 [256,256] row-major) into fp16 fragment-contiguous
// layout: sw = (k>>3)*2048 + n*8 + (k&7). Used as MFMA B-frags by the GEMMs
// and as per-lane weight columns by the rnn kernel.
// ---------------------------------------------------------------------------
__global__ void prep_kernel(const float* __restrict__ w0, const float* __restrict__ wq,
                            const float* __restrict__ u0, const float* __restrict__ w1,
                            const float* __restrict__ u1,
                            _Float16* __restrict__ B0, _Float16* __restrict__ Bq,
                            _Float16* __restrict__ U0, _Float16* __restrict__ W1,
                            _Float16* __restrict__ U1)
{
  int i = blockIdx.x * 256 + threadIdx.x;
  for (int idx = i; idx < 65536; idx += 64 * 256){
    int k = idx >> 8, n = idx & 255;
    int sw = (k >> 3) * 2048 + n * 8 + (k & 7);
    B0[sw] = (_Float16)w0[idx];
    Bq[sw] = (_Float16)wq[idx];
    U0[sw] = (_Float16)u0[idx];
    W1[sw] = (_Float16)w1[idx];
    U1[sw] = (_Float16)u1[idx];
  }
}

// ---------------------------------------------------------------------------
// C[131072,256] = A[131072,256] @ B[256,256] + bias, fp16 MFMA 32x32x16.
// 512 blocks x 512 thr; each wave owns a 32-row x 256-col strip (8 col-tiles,
// 128 acc VGPRs). A-frags direct from global; B-frags from pre-swizzled global
// fp16 (L2-resident), perfectly coalesced. No LDS.
// ---------------------------------------------------------------------------
template<bool A_FP32, bool C_FP16>
__launch_bounds__(512)
__global__ void gemm256(const void* __restrict__ Ap,
                        const _Float16* __restrict__ Bsw,
                        const float* __restrict__ bias,
                        void* __restrict__ Cp)
{
  const int wave = threadIdx.x >> 6;
  const int lane = threadIdx.x & 63;
  const int r  = lane & 31;     // A row / B col / C col within tile
  const int hf = lane >> 5;     // k-half selector
  const size_t rowt = (size_t)blockIdx.x * 256 + (size_t)wave * 32;

  floatx16 acc[8];
  #pragma unroll
  for (int i = 0; i < 8; ++i)
    #pragma unroll
    for (int j = 0; j < 16; ++j) acc[i][j] = 0.f;

  const size_t arow = rowt + (size_t)r;
  #pragma unroll
  for (int ks = 0; ks < 16; ++ks){
    half8_t af;
    if (A_FP32){
      const float* A = (const float*)Ap;
      const floatx4* p = (const floatx4*)(A + arow * 256 + ks * 16 + hf * 8);
      floatx4 v0 = p[0], v1 = p[1];
      floatx8 v = __builtin_shufflevector(v0, v1, 0, 1, 2, 3, 4, 5, 6, 7);
      af = __builtin_convertvector(v, half8_t);
    } else {
      const _Float16* A = (const _Float16*)Ap;
      af = *(const half8_t*)(A + arow * 256 + ks * 16 + hf * 8);
    }
    #pragma unroll
    for (int ct = 0; ct < 8; ++ct){
      half8_t bf = *(const half8_t*)(Bsw + (size_t)(ks * 2 + hf) * 2048 + (ct * 32 + r) * 8);
      acc[ct] = __builtin_amdgcn_mfma_f32_32x32x16_f16(af, bf, acc[ct], 0, 0, 0);
    }
  }

  #pragma unroll
  for (int ct = 0; ct < 8; ++ct){
    const int col = ct * 32 + r;
    const float bc = bias[col];
    #pragma unroll
    for (int reg = 0; reg < 16; ++reg){
      const int rl = (reg & 3) + 8 * (reg >> 2) + 4 * hf;   // verified 32x32 C/D map
      const size_t idx = (rowt + rl) * 256 + col;
      float v = acc[ct][reg] + bc;
      if (C_FP16) ((_Float16*)Cp)[idx] = (_Float16)v;
      else        ((float*)Cp)[idx]    = v;
    }
  }
}

extern "C" void kernel_launch(void* const* d_in, const int* in_sizes, int n_in,
                              void* d_out, int out_size, void* d_ws, size_t ws_size,
                              hipStream_t stream)
{
  (void)in_sizes; (void)n_in; (void)out_size;

  const float* x    = (const float*)d_in[0];
  const float* w_h0 = (const float*)d_in[1];
  const float* u_h0 = (const float*)d_in[2];
  const float* b_h0 = (const float*)d_in[3];
  const float* w_h1 = (const float*)d_in[4];
  const float* u_h1 = (const float*)d_in[5];
  const float* b_h1 = (const float*)d_in[6];
  const float* w_q  = (const float*)d_in[7];
  const float* b_q  = (const float*)d_in[8];

  const size_t MSH = (size_t)NB * S_LEN * HD;          // 33,554,432 elements
  float* y    = (float*)d_out;                         // [B,S,O] fp32
  float* hfin = y + MSH;                               // [B,2,H] fp32

  // Scratch layout. H1 always in ws. A0 in ws if it fits, else in d_out's low
  // half (A0 fully consumed by rnn before the Y-GEMM overwrites d_out).
  // 5 swizzled fp16 weight images (128KB each) follow.
  _Float16* H1 = (_Float16*)d_ws;
  _Float16 *A0, *B0sw, *Bqsw, *U0sw, *W1sw, *U1sw;
  if (ws_size >= (MSH * 2 + 5 * 65536) * sizeof(_Float16)){
    A0   = H1 + MSH;
    B0sw = A0 + MSH;
  } else {
    A0   = (_Float16*)d_out;    // 67MB fp16 in the 134MB output buffer
    B0sw = H1 + MSH;
  }
  Bqsw = B0sw + 65536;
  U0sw = Bqsw + 65536;
  W1sw = U0sw + 65536;
  U1sw = W1sw + 65536;

  prep_kernel<<<dim3(64), dim3(256), 0, stream>>>(w_h0, w_q, u_h0, w_h1, u_h1,
                                                  B0sw, Bqsw, U0sw, W1sw, U1sw);
  gemm256<true, true><<<dim3(512), dim3(512), 0, stream>>>((const void*)x, B0sw, b_h0, (void*)A0);
  rnn_kernel<<<dim3(NB), dim3(768), 0, stream>>>(A0, U0sw, W1sw, U1sw, b_h1, H1, hfin);
  gemm256<false, false><<<dim3(512), dim3(512), 0, stream>>>((const void*)H1, Bqsw, b_q, (void*)y);
}